// Round 1
// baseline (624.312 us; speedup 1.0000x reference)
//
#include <hip/hip_runtime.h>
#include <hip/hip_bf16.h>

#define N_NODES 100000
#define N0_ROWS 60000
#define N1_ROWS 40000
#define NE 1600000
#define HD 128

typedef __attribute__((ext_vector_type(8))) short short8;
typedef __attribute__((ext_vector_type(4))) float f32x4;

__device__ __forceinline__ float bf16lo(unsigned v) { return __uint_as_float(v << 16); }
__device__ __forceinline__ float bf16hi(unsigned v) { return __uint_as_float(v & 0xFFFF0000u); }

__device__ __forceinline__ unsigned short f2bf_rne(float f) {
    unsigned u = __float_as_uint(f);
    return (unsigned short)((u + 0x7FFFu + ((u >> 16) & 1u)) >> 16);
}
__device__ __forceinline__ unsigned pack2_rne(float lo, float hi) {
    unsigned a = __float_as_uint(lo); a = (a + 0x7FFFu + ((a >> 16) & 1u)) >> 16;
    unsigned b = __float_as_uint(hi); b = (b + 0x7FFFu + ((b >> 16) & 1u)) & 0xFFFF0000u;
    return (a & 0xFFFFu) | b;
}
__device__ __forceinline__ float sigmoidf_(float v) { return 1.0f / (1.0f + __expf(-v)); }

// ---------------- CSR build ----------------
__global__ void k_deg(const int* __restrict__ dst, int* __restrict__ deg) {
    int stride = gridDim.x * blockDim.x;
    for (int e = blockIdx.x * blockDim.x + threadIdx.x; e < NE; e += stride)
        atomicAdd(&deg[dst[e]], 1);
}

__global__ __launch_bounds__(1024) void k_scan(const int* __restrict__ deg,
                                               int* __restrict__ rowptr,
                                               float* __restrict__ invd) {
    __shared__ int wsum[16];
    __shared__ int s_carry;
    int tid = threadIdx.x, lane = tid & 63, wid = tid >> 6;
    if (tid == 0) s_carry = 0;
    __syncthreads();
    for (int base = 0; base < N_NODES; base += 1024) {
        int i = base + tid;
        int v = (i < N_NODES) ? deg[i] : 0;
        int s = v;
        #pragma unroll
        for (int off = 1; off < 64; off <<= 1) {
            int t = __shfl_up(s, off);
            if (lane >= off) s += t;
        }
        if (lane == 63) wsum[wid] = s;
        __syncthreads();
        if (wid == 0) {
            int ws = (lane < 16) ? wsum[lane] : 0;
            #pragma unroll
            for (int off = 1; off < 16; off <<= 1) {
                int t = __shfl_up(ws, off);
                if (lane >= off) ws += t;
            }
            if (lane < 16) wsum[lane] = ws;
        }
        __syncthreads();
        int carry = s_carry;
        int woff = (wid == 0) ? 0 : wsum[wid - 1];
        if (i < N_NODES) {
            rowptr[i] = carry + woff + s - v;   // exclusive
            invd[i] = 1.0f / fmaxf((float)v, 1.0f);
        }
        __syncthreads();
        if (tid == 0) s_carry = carry + wsum[15];
        __syncthreads();
    }
    if (threadIdx.x == 0) rowptr[N_NODES] = s_carry;
}

__global__ void k_fill(const int* __restrict__ src, const int* __restrict__ dst,
                       const int* __restrict__ rowptr, int* __restrict__ cnt,
                       int* __restrict__ eidx) {
    int stride = gridDim.x * blockDim.x;
    for (int e = blockIdx.x * blockDim.x + threadIdx.x; e < NE; e += stride) {
        int d = dst[e];
        int p = rowptr[d] + atomicAdd(&cnt[d], 1);
        eidx[p] = src[e];
    }
}

// ---------------- weight prep: transpose + f32->bf16 (RNE) ----------------
// Wt[n*K + k] = bf16(W[k*N + n])
__global__ void prep_w(const float* __restrict__ W, unsigned short* __restrict__ Wt, int K, int N) {
    int total = K * N;
    int stride = gridDim.x * blockDim.x;
    for (int i = blockIdx.x * blockDim.x + threadIdx.x; i < total; i += stride) {
        int n = i / K, k = i - n * K;
        Wt[i] = f2bf_rne(W[k * N + n]);
    }
}

// ---------------- input projection: feat(f32) @ W -> h(bf16), +bias, no act ----------------
template <int K>
__global__ __launch_bounds__(256, 2) void k_proj(const float* __restrict__ feat,
                                                 const unsigned short* __restrict__ Wt,
                                                 const float* __restrict__ bias,
                                                 unsigned short* __restrict__ hout,
                                                 int rows, int row_off) {
    const int lane = threadIdx.x & 63, wid = threadIdx.x >> 6;
    const int g = lane >> 4, r16 = lane & 15;
    const int colbase = wid * 32;
    constexpr int KC = K / 32;

    short8 fb[2][KC];
    #pragma unroll
    for (int nt = 0; nt < 2; ++nt) {
        int n = colbase + nt * 16 + r16;
        #pragma unroll
        for (int kc = 0; kc < KC; ++kc)
            fb[nt][kc] = *reinterpret_cast<const short8*>(Wt + (size_t)n * K + kc * 32 + g * 8);
    }
    float bv[2];
    bv[0] = bias[colbase + r16];
    bv[1] = bias[colbase + 16 + r16];

    const int ntiles = rows / 16;
    for (int tile = blockIdx.x; tile < ntiles; tile += gridDim.x) {
        const float* ap = feat + (size_t)(tile * 16 + r16) * K;
        f32x4 acc0 = {0.f, 0.f, 0.f, 0.f};
        f32x4 acc1 = {0.f, 0.f, 0.f, 0.f};
        #pragma unroll
        for (int kc = 0; kc < KC; ++kc) {
            const float4* p = reinterpret_cast<const float4*>(ap + kc * 32 + g * 8);
            float4 x0 = p[0], x1 = p[1];
            union { unsigned u[4]; short8 v; } cvt;
            cvt.u[0] = __builtin_amdgcn_perm(__float_as_uint(x0.y), __float_as_uint(x0.x), 0x07060302u);
            cvt.u[1] = __builtin_amdgcn_perm(__float_as_uint(x0.w), __float_as_uint(x0.z), 0x07060302u);
            cvt.u[2] = __builtin_amdgcn_perm(__float_as_uint(x1.y), __float_as_uint(x1.x), 0x07060302u);
            cvt.u[3] = __builtin_amdgcn_perm(__float_as_uint(x1.w), __float_as_uint(x1.z), 0x07060302u);
            acc0 = __builtin_amdgcn_mfma_f32_16x16x32_bf16(cvt.v, fb[0][kc], acc0, 0, 0, 0);
            acc1 = __builtin_amdgcn_mfma_f32_16x16x32_bf16(cvt.v, fb[1][kc], acc1, 0, 0, 0);
        }
        #pragma unroll
        for (int r = 0; r < 4; ++r) {
            size_t orow = (size_t)(row_off + tile * 16 + g * 4 + r);
            hout[orow * HD + colbase + r16]      = f2bf_rne(acc0[r] + bv[0]);
            hout[orow * HD + colbase + 16 + r16] = f2bf_rne(acc1[r] + bv[1]);
        }
    }
}

// ---------------- aggregate: x = h + inv_deg * sum_{j in N(i)} h[j] ----------------
__global__ __launch_bounds__(256, 4) void k_agg(const unsigned short* __restrict__ h,
                                                const int* __restrict__ rowptr,
                                                const int* __restrict__ eidx,
                                                const float* __restrict__ invd,
                                                unsigned short* __restrict__ x) {
    const unsigned* hp = reinterpret_cast<const unsigned*>(h);
    unsigned* xp = reinterpret_cast<unsigned*>(x);
    int lane = threadIdx.x & 63, wid = threadIdx.x >> 6;
    int nwaves = gridDim.x * 4;
    for (int node = blockIdx.x * 4 + wid; node < N_NODES; node += nwaves) {
        int rp0 = rowptr[node], rp1 = rowptr[node + 1];
        float a0 = 0.f, a1 = 0.f;
        for (int base = rp0; base < rp1; base += 64) {
            int m = rp1 - base; if (m > 64) m = 64;
            int idx = (lane < m) ? eidx[base + lane] : 0;
            int t = 0;
            for (; t + 4 <= m; t += 4) {
                int j0 = __shfl(idx, t), j1 = __shfl(idx, t + 1);
                int j2 = __shfl(idx, t + 2), j3 = __shfl(idx, t + 3);
                unsigned v0 = hp[(size_t)j0 * 64 + lane];
                unsigned v1 = hp[(size_t)j1 * 64 + lane];
                unsigned v2 = hp[(size_t)j2 * 64 + lane];
                unsigned v3 = hp[(size_t)j3 * 64 + lane];
                a0 += bf16lo(v0) + bf16lo(v1) + bf16lo(v2) + bf16lo(v3);
                a1 += bf16hi(v0) + bf16hi(v1) + bf16hi(v2) + bf16hi(v3);
            }
            for (; t < m; ++t) {
                int j = __shfl(idx, t);
                unsigned v = hp[(size_t)j * 64 + lane];
                a0 += bf16lo(v); a1 += bf16hi(v);
            }
        }
        unsigned hv = hp[(size_t)node * 64 + lane];
        float s = invd[node];
        xp[(size_t)node * 64 + lane] = pack2_rne(bf16lo(hv) + s * a0, bf16hi(hv) + s * a1);
    }
}

// ---------------- gin GEMM: h = sigmoid(x @ W + b), 128->128, bf16 out ----------------
__global__ __launch_bounds__(256, 4) void k_gin_gemm(const unsigned short* __restrict__ x,
                                                     const unsigned short* __restrict__ Wt,
                                                     const float* __restrict__ bias,
                                                     unsigned short* __restrict__ hout) {
    const int lane = threadIdx.x & 63, wid = threadIdx.x >> 6;
    const int g = lane >> 4, r16 = lane & 15;
    const int colbase = wid * 32;

    short8 fb[2][4];
    #pragma unroll
    for (int nt = 0; nt < 2; ++nt) {
        int n = colbase + nt * 16 + r16;
        #pragma unroll
        for (int kc = 0; kc < 4; ++kc)
            fb[nt][kc] = *reinterpret_cast<const short8*>(Wt + (size_t)n * HD + kc * 32 + g * 8);
    }
    float bv[2];
    bv[0] = bias[colbase + r16];
    bv[1] = bias[colbase + 16 + r16];

    const int ntiles = N_NODES / 16;  // 6250
    for (int tile = blockIdx.x; tile < ntiles; tile += gridDim.x) {
        const unsigned short* ap = x + (size_t)(tile * 16 + r16) * HD;
        f32x4 acc0 = {0.f, 0.f, 0.f, 0.f};
        f32x4 acc1 = {0.f, 0.f, 0.f, 0.f};
        #pragma unroll
        for (int kc = 0; kc < 4; ++kc) {
            short8 fa = *reinterpret_cast<const short8*>(ap + kc * 32 + g * 8);
            acc0 = __builtin_amdgcn_mfma_f32_16x16x32_bf16(fa, fb[0][kc], acc0, 0, 0, 0);
            acc1 = __builtin_amdgcn_mfma_f32_16x16x32_bf16(fa, fb[1][kc], acc1, 0, 0, 0);
        }
        #pragma unroll
        for (int r = 0; r < 4; ++r) {
            size_t orow = (size_t)(tile * 16 + g * 4 + r);
            hout[orow * HD + colbase + r16]      = f2bf_rne(sigmoidf_(acc0[r] + bv[0]));
            hout[orow * HD + colbase + 16 + r16] = f2bf_rne(sigmoidf_(acc1[r] + bv[1]));
        }
    }
}

// ---------------- output GEMM: out = sigmoid(x @ Wout + b), 128->16, f32 out ----------------
__global__ __launch_bounds__(256, 4) void k_out_gemm(const unsigned short* __restrict__ x,
                                                     const unsigned short* __restrict__ Wt,
                                                     const float* __restrict__ bias,
                                                     float* __restrict__ out) {
    const int lane = threadIdx.x & 63, wid = threadIdx.x >> 6;
    const int g = lane >> 4, r16 = lane & 15;

    short8 fb[4];
    #pragma unroll
    for (int kc = 0; kc < 4; ++kc)
        fb[kc] = *reinterpret_cast<const short8*>(Wt + (size_t)r16 * HD + kc * 32 + g * 8);
    float bv = bias[r16];

    const int ntiles = N_NODES / 16;  // 6250, one tile per wave
    for (int tile = blockIdx.x * 4 + wid; tile < ntiles; tile += gridDim.x * 4) {
        const unsigned short* ap = x + (size_t)(tile * 16 + r16) * HD;
        f32x4 acc = {0.f, 0.f, 0.f, 0.f};
        #pragma unroll
        for (int kc = 0; kc < 4; ++kc) {
            short8 fa = *reinterpret_cast<const short8*>(ap + kc * 32 + g * 8);
            acc = __builtin_amdgcn_mfma_f32_16x16x32_bf16(fa, fb[kc], acc, 0, 0, 0);
        }
        #pragma unroll
        for (int r = 0; r < 4; ++r)
            out[(size_t)(tile * 16 + g * 4 + r) * 16 + r16] = sigmoidf_(acc[r] + bv);
    }
}

extern "C" void kernel_launch(void* const* d_in, const int* in_sizes, int n_in,
                              void* d_out, int out_size, void* d_ws, size_t ws_size,
                              hipStream_t stream) {
    const float* feat0 = (const float*)d_in[0];
    const float* feat1 = (const float*)d_in[1];
    const int*   src   = (const int*)d_in[2];
    const int*   dst   = (const int*)d_in[3];
    const float* Wfc0  = (const float*)d_in[4];
    const float* bfc0  = (const float*)d_in[5];
    const float* Wfc1  = (const float*)d_in[6];
    const float* bfc1  = (const float*)d_in[7];
    const float* Wg0   = (const float*)d_in[8];
    const float* bg0   = (const float*)d_in[9];
    const float* Wg1   = (const float*)d_in[10];
    const float* bg1   = (const float*)d_in[11];
    const float* Wout  = (const float*)d_in[12];
    const float* bout  = (const float*)d_in[13];

    char* w = (char*)d_ws;
    auto alloc = [&](size_t bytes) {
        char* p = w;
        w += (bytes + 255) & ~(size_t)255;
        return p;
    };
    unsigned short* h      = (unsigned short*)alloc((size_t)N_NODES * HD * 2);
    unsigned short* x      = (unsigned short*)alloc((size_t)N_NODES * HD * 2);
    int*   deg    = (int*)alloc((size_t)N_NODES * 4);
    int*   cnt    = (int*)alloc((size_t)N_NODES * 4);
    int*   rowptr = (int*)alloc((size_t)(N_NODES + 1) * 4);
    float* invd   = (float*)alloc((size_t)N_NODES * 4);
    int*   eidx   = (int*)alloc((size_t)NE * 4);
    unsigned short* Wt_fc0 = (unsigned short*)alloc(512 * 128 * 2);
    unsigned short* Wt_fc1 = (unsigned short*)alloc(256 * 128 * 2);
    unsigned short* Wt_g0  = (unsigned short*)alloc(128 * 128 * 2);
    unsigned short* Wt_g1  = (unsigned short*)alloc(128 * 128 * 2);
    unsigned short* Wt_out = (unsigned short*)alloc(128 * 16 * 2);

    hipMemsetAsync(deg, 0, (size_t)N_NODES * 4, stream);
    hipMemsetAsync(cnt, 0, (size_t)N_NODES * 4, stream);

    k_deg<<<2048, 256, 0, stream>>>(dst, deg);
    k_scan<<<1, 1024, 0, stream>>>(deg, rowptr, invd);
    k_fill<<<2048, 256, 0, stream>>>(src, dst, rowptr, cnt, eidx);

    prep_w<<<64, 256, 0, stream>>>(Wfc0, Wt_fc0, 512, 128);
    prep_w<<<64, 256, 0, stream>>>(Wfc1, Wt_fc1, 256, 128);
    prep_w<<<64, 256, 0, stream>>>(Wg0,  Wt_g0,  128, 128);
    prep_w<<<64, 256, 0, stream>>>(Wg1,  Wt_g1,  128, 128);
    prep_w<<<16, 256, 0, stream>>>(Wout, Wt_out, 128, 16);

    k_proj<512><<<512, 256, 0, stream>>>(feat0, Wt_fc0, bfc0, h, N0_ROWS, 0);
    k_proj<256><<<512, 256, 0, stream>>>(feat1, Wt_fc1, bfc1, h, N1_ROWS, N0_ROWS);

    k_agg<<<2048, 256, 0, stream>>>(h, rowptr, eidx, invd, x);
    k_gin_gemm<<<1024, 256, 0, stream>>>(x, Wt_g0, bg0, h);
    k_agg<<<2048, 256, 0, stream>>>(h, rowptr, eidx, invd, x);
    k_gin_gemm<<<1024, 256, 0, stream>>>(x, Wt_g1, bg1, h);
    k_agg<<<2048, 256, 0, stream>>>(h, rowptr, eidx, invd, x);
    k_out_gemm<<<1024, 256, 0, stream>>>(x, Wt_out, bout, (float*)d_out);
}